// Round 2
// baseline (492.602 us; speedup 1.0000x reference)
//
#include <hip/hip_runtime.h>
#include <hip/hip_bf16.h>

typedef __attribute__((ext_vector_type(8))) short bf16x8;
typedef __attribute__((ext_vector_type(4))) float f32x4;

__device__ __forceinline__ f32x4 mfma16(bf16x8 a, bf16x8 b, f32x4 c) {
  return __builtin_amdgcn_mfma_f32_16x16x32_bf16(a, b, c, 0, 0, 0);
}

__device__ __forceinline__ void gload_lds16(const void* g, void* l) {
  __builtin_amdgcn_global_load_lds(
      (__attribute__((address_space(1))) void*)(g),
      (__attribute__((address_space(3))) void*)(l), 16, 0, 0);
}

__device__ __forceinline__ unsigned short f2bf(float f) {
  union { __hip_bfloat16 h; unsigned short u; } cv;
  cv.h = __float2bfloat16(f);
  return cv.u;
}

__device__ __forceinline__ void split2(float v, unsigned short& hb, unsigned short& lb) {
  __hip_bfloat16 hh = __float2bfloat16(v);
  union { __hip_bfloat16 h; unsigned short u; } cv;
  cv.h = hh;
  hb = cv.u;
  lb = f2bf(v - __bfloat162float(hh));
}

__device__ __forceinline__ float gelu_f(float v) {
  float u = 0.7978845608028654f * (v + 0.044715f * v * v * v);
  return 0.5f * v * (1.0f + tanhf(u));
}

// ---------------- transpose + cast split: W f32 [K][N] -> hi/lo bf16 [N][K] ----------------
__global__ __launch_bounds__(256) void transpose_cast_split(
    const float* __restrict__ in, unsigned short* __restrict__ outh,
    unsigned short* __restrict__ outl, int K, int N) {
  __shared__ float tile[32][33];
  const int n0 = blockIdx.x * 32, k0 = blockIdx.y * 32;
  const int tx = threadIdx.x & 31, ty = threadIdx.x >> 5;  // ty 0..7
#pragma unroll
  for (int i = 0; i < 32; i += 8)
    tile[ty + i][tx] = in[(size_t)(k0 + ty + i) * N + (n0 + tx)];
  __syncthreads();
#pragma unroll
  for (int i = 0; i < 32; i += 8) {
    unsigned short hb, lb;
    split2(tile[tx][ty + i], hb, lb);
    const size_t idx = (size_t)(n0 + ty + i) * K + (k0 + tx);
    outh[idx] = hb;
    outl[idx] = lb;
  }
}

// ---------------- LayerNorm (C=768) f32 -> split bf16 ----------------
__global__ __launch_bounds__(192) void ln_split(
    const float* __restrict__ x, const float* __restrict__ w,
    const float* __restrict__ bb, unsigned short* __restrict__ outh,
    unsigned short* __restrict__ outl) {
  const int row = blockIdx.x;
  const int t = threadIdx.x;  // 0..191, 4 floats each
  const float4 v = ((const float4*)(x + (size_t)row * 768))[t];
  float s = v.x + v.y + v.z + v.w;
  float q = v.x * v.x + v.y * v.y + v.z * v.z + v.w * v.w;
#pragma unroll
  for (int off = 1; off < 64; off <<= 1) {
    s += __shfl_xor(s, off);
    q += __shfl_xor(q, off);
  }
  __shared__ float ss[3], qq[3];
  const int wid = t >> 6;
  if ((t & 63) == 0) { ss[wid] = s; qq[wid] = q; }
  __syncthreads();
  const float S = ss[0] + ss[1] + ss[2];
  const float Q = qq[0] + qq[1] + qq[2];
  const float mu = S * (1.0f / 768.0f);
  const float var = Q * (1.0f / 768.0f) - mu * mu;
  const float rstd = rsqrtf(var + 1e-5f);
  const float4 wv = ((const float4*)w)[t];
  const float4 bv = ((const float4*)bb)[t];
  float r0 = (v.x - mu) * rstd * wv.x + bv.x;
  float r1 = (v.y - mu) * rstd * wv.y + bv.y;
  float r2 = (v.z - mu) * rstd * wv.z + bv.z;
  float r3 = (v.w - mu) * rstd * wv.w + bv.w;
  ushort4 oh, ol;
  split2(r0, oh.x, ol.x);
  split2(r1, oh.y, ol.y);
  split2(r2, oh.z, ol.z);
  split2(r3, oh.w, ol.w);
  ((ushort4*)(outh + (size_t)row * 768))[t] = oh;
  ((ushort4*)(outl + (size_t)row * 768))[t] = ol;
}

// ---------------- GEMM: C = A * Bt^T + bias (split-bf16 operands, f32-grade) ----------------
// EPI 0: bf16 store; 1: gelu + bf16 store; 2: f32 store with f32 residual add
// ASPLIT 1: A has hi+lo (3 mfma); 0: A hi only (2 mfma).
template <int EPI, int ASPLIT>
__global__ __launch_bounds__(256) void gemm_bt(
    const unsigned short* __restrict__ Ah, const unsigned short* __restrict__ Al,
    const unsigned short* __restrict__ Bh, const unsigned short* __restrict__ Bl,
    const float* __restrict__ bias, const float* __restrict__ resid,
    void* __restrict__ outp, int M, int N, int K) {
  __shared__ __align__(16) unsigned short ldsAh[128 * 32];
  __shared__ __align__(16) unsigned short ldsAl[128 * 32];
  __shared__ __align__(16) unsigned short ldsBh[128 * 32];
  __shared__ __align__(16) unsigned short ldsBl[128 * 32];
  const int tid = threadIdx.x;
  const int lane = tid & 63, wid = tid >> 6;
  const int wr = wid >> 1, wc = wid & 1;  // wave -> 64x64 sub-tile
  const int m0 = blockIdx.y * 128, n0 = blockIdx.x * 128;
  const int srow = lane >> 2, sk = (lane & 3) * 8;  // staging: 16 rows/wave, 16B/lane
  const size_t arow = (size_t)(m0 + wid * 16 + srow) * K + sk;
  const size_t brow = (size_t)(n0 + wid * 16 + srow) * K + sk;
  const unsigned short* Agh = Ah + arow;
  const unsigned short* Agl = Al + arow;  // valid only if ASPLIT
  const unsigned short* Bgh = Bh + brow;
  const unsigned short* Bgl = Bl + brow;
  char* AhW = (char*)ldsAh + wid * 1024;
  char* AlW = (char*)ldsAl + wid * 1024;
  char* BhW = (char*)ldsBh + wid * 1024;
  char* BlW = (char*)ldsBl + wid * 1024;
  const int rl = lane & 15, g = lane >> 4;
  const int koff = g * 16;  // byte offset of k-chunk within 64B row

  f32x4 acc[4][4];
#pragma unroll
  for (int m = 0; m < 4; ++m)
#pragma unroll
    for (int n = 0; n < 4; ++n) acc[m][n] = 0.0f;

  for (int k0 = 0; k0 < K; k0 += 32) {
    gload_lds16(Agh, AhW);
    gload_lds16(Agh + (size_t)64 * K, AhW + 4096);
    if (ASPLIT) {
      gload_lds16(Agl, AlW);
      gload_lds16(Agl + (size_t)64 * K, AlW + 4096);
      Agl += 32;
    }
    gload_lds16(Bgh, BhW);
    gload_lds16(Bgh + (size_t)64 * K, BhW + 4096);
    gload_lds16(Bgl, BlW);
    gload_lds16(Bgl + (size_t)64 * K, BlW + 4096);
    Agh += 32;
    Bgh += 32;
    Bgl += 32;
    __syncthreads();
    bf16x8 fah[4], fal[4], fbh[4], fbl[4];
#pragma unroll
    for (int m = 0; m < 4; ++m) {
      const int off = (wr * 64 + m * 16 + rl) * 64 + koff;
      fah[m] = *(const bf16x8*)((const char*)ldsAh + off);
      if (ASPLIT) fal[m] = *(const bf16x8*)((const char*)ldsAl + off);
    }
#pragma unroll
    for (int n = 0; n < 4; ++n) {
      const int off = (wc * 64 + n * 16 + rl) * 64 + koff;
      fbh[n] = *(const bf16x8*)((const char*)ldsBh + off);
      fbl[n] = *(const bf16x8*)((const char*)ldsBl + off);
    }
#pragma unroll
    for (int m = 0; m < 4; ++m)
#pragma unroll
      for (int n = 0; n < 4; ++n) {
        acc[m][n] = mfma16(fah[m], fbh[n], acc[m][n]);
        acc[m][n] = mfma16(fah[m], fbl[n], acc[m][n]);
        if (ASPLIT) acc[m][n] = mfma16(fal[m], fbh[n], acc[m][n]);
      }
    __syncthreads();
  }

  __hip_bfloat16* outb16 = (__hip_bfloat16*)outp;
  float* outf = (float*)outp;
#pragma unroll
  for (int n = 0; n < 4; ++n) {
    const int col = n0 + wc * 64 + n * 16 + rl;
    const float bia = bias[col];
#pragma unroll
    for (int m = 0; m < 4; ++m) {
      const int row_base = m0 + wr * 64 + m * 16 + g * 4;
#pragma unroll
      for (int r = 0; r < 4; ++r) {
        float val = acc[m][n][r] + bia;
        const size_t idx = (size_t)(row_base + r) * N + col;
        if (EPI == 1) val = gelu_f(val);
        if (EPI == 2)
          outf[idx] = resid[idx] + val;
        else
          outb16[idx] = __float2bfloat16(val);
      }
    }
  }
}

// ---------------- fused causal attention (flash-style) ----------------
// qkv bf16 [B*T, 2304]; y split bf16 [B*T, 768]. grid (32 qtiles, 24 bh), 256 thr.
__global__ __launch_bounds__(256) void attn_kernel(
    const unsigned short* __restrict__ qkv, unsigned short* __restrict__ yh,
    unsigned short* __restrict__ yl) {
  const int T = 2048, C3 = 2304, NH = 12;
  const int qt = blockIdx.x, bh = blockIdx.y;
  const int b = bh / NH, h = bh % NH;
  const int tid = threadIdx.x, lane = tid & 63, w = tid >> 6;
  const int rl = lane & 15, g = lane >> 4;
  __shared__ __align__(16) unsigned short Kl[32 * 72];      // [kv 32][d 64 pad 72]
  __shared__ __align__(16) unsigned short Vt[64 * 40];      // [d 64][kv 32 pad 40]
  __shared__ __align__(16) unsigned short Pl[4 * 16 * 40];  // per wave [16 q][32 kv pad 40]
  const size_t base = (size_t)b * T * C3;
  const int hq = h * 64, hk = 768 + h * 64, hv = 1536 + h * 64;
  const int qr0 = qt * 64 + w * 16;

  bf16x8 qf[2];
#pragma unroll
  for (int c = 0; c < 2; ++c)
    qf[c] = *(const bf16x8*)(qkv + base + (size_t)(qr0 + rl) * C3 + hq + 32 * c + 8 * g);

  f32x4 o[4];
  float m_r[4], s_r[4];
#pragma unroll
  for (int i = 0; i < 4; ++i) { o[i] = 0.0f; m_r[i] = -1e30f; s_r[i] = 0.0f; }

  const int kend = qt * 64 + 64;
  const int krow = tid >> 3, kc = (tid & 7) * 8;  // staging: 32 rows x 64 cols

  for (int kv0 = 0; kv0 < kend; kv0 += 32) {
    // stage K (row-major, padded) and V (transposed, padded)
    bf16x8 kval = *(const bf16x8*)(qkv + base + (size_t)(kv0 + krow) * C3 + hk + kc);
    *(bf16x8*)(&Kl[krow * 72 + kc]) = kval;
    bf16x8 vval = *(const bf16x8*)(qkv + base + (size_t)(kv0 + krow) * C3 + hv + kc);
#pragma unroll
    for (int i = 0; i < 8; ++i) Vt[(kc + i) * 40 + krow] = (unsigned short)vval[i];
    __syncthreads();

    // S = Q K^T  (two 16-col frags covering the 32 kv cols)
    f32x4 s0 = 0.0f, s1 = 0.0f;
#pragma unroll
    for (int c = 0; c < 2; ++c) {
      bf16x8 kb0 = *(const bf16x8*)(&Kl[rl * 72 + 32 * c + 8 * g]);
      bf16x8 kb1 = *(const bf16x8*)(&Kl[(16 + rl) * 72 + 32 * c + 8 * g]);
      s0 = mfma16(qf[c], kb0, s0);
      s1 = mfma16(qf[c], kb1, s1);
    }

    unsigned short* PlW = Pl + (w * 16) * 40;
#pragma unroll
    for (int r = 0; r < 4; ++r) {
      const int qrow = qr0 + g * 4 + r;
      float a0 = s0[r] * 0.125f;
      a0 = (kv0 + rl > qrow) ? -1e30f : a0;
      float a1 = s1[r] * 0.125f;
      a1 = (kv0 + 16 + rl > qrow) ? -1e30f : a1;
      float vmax = fmaxf(a0, a1);
#pragma unroll
      for (int off = 1; off < 16; off <<= 1) vmax = fmaxf(vmax, __shfl_xor(vmax, off));
      const float mnew = fmaxf(m_r[r], vmax);
      const float fs = __expf(m_r[r] - mnew);
      const float p0 = __expf(a0 - mnew);
      const float p1 = __expf(a1 - mnew);
      float rs = p0 + p1;
#pragma unroll
      for (int off = 1; off < 16; off <<= 1) rs += __shfl_xor(rs, off);
      s_r[r] = s_r[r] * fs + rs;
      m_r[r] = mnew;
#pragma unroll
      for (int nf = 0; nf < 4; ++nf) o[nf][r] *= fs;
      PlW[(g * 4 + r) * 40 + rl] = f2bf(p0);
      PlW[(g * 4 + r) * 40 + 16 + rl] = f2bf(p1);
    }
    __syncthreads();  // P visible (and staging consumers done)

    // O += P V
    bf16x8 pa = *(const bf16x8*)(Pl + (w * 16 + rl) * 40 + 8 * g);
#pragma unroll
    for (int nf = 0; nf < 4; ++nf) {
      bf16x8 vb = *(const bf16x8*)(Vt + (nf * 16 + rl) * 40 + 8 * g);
      o[nf] = mfma16(pa, vb, o[nf]);
    }
    __syncthreads();  // before next tile overwrites K/V
  }

#pragma unroll
  for (int nf = 0; nf < 4; ++nf)
#pragma unroll
    for (int r = 0; r < 4; ++r) {
      const float val = o[nf][r] / s_r[r];
      const size_t idx = (size_t)(b * T + qr0 + g * 4 + r) * 768 + hq + nf * 16 + rl;
      unsigned short hb, lb;
      split2(val, hb, lb);
      yh[idx] = hb;
      yl[idx] = lb;
    }
}

// ---------------- host launch ----------------
extern "C" void kernel_launch(void* const* d_in, const int* in_sizes, int n_in,
                              void* d_out, int out_size, void* d_ws, size_t ws_size,
                              hipStream_t stream) {
  const float* x    = (const float*)d_in[0];
  const float* ln1w = (const float*)d_in[1];
  const float* ln1b = (const float*)d_in[2];
  const float* qkvw = (const float*)d_in[3];
  const float* qkvb = (const float*)d_in[4];
  const float* outw = (const float*)d_in[5];
  const float* outb = (const float*)d_in[6];
  const float* fc1w = (const float*)d_in[7];
  const float* fc1b = (const float*)d_in[8];
  const float* fc2w = (const float*)d_in[9];
  const float* fc2b = (const float*)d_in[10];
  float* outp = (float*)d_out;

  char* ws = (char*)d_ws;
  unsigned short* qkvw_h = (unsigned short*)ws;  ws += (size_t)2304 * 768 * 2;
  unsigned short* qkvw_l = (unsigned short*)ws;  ws += (size_t)2304 * 768 * 2;
  unsigned short* outw_h = (unsigned short*)ws;  ws += (size_t)768 * 768 * 2;
  unsigned short* outw_l = (unsigned short*)ws;  ws += (size_t)768 * 768 * 2;
  unsigned short* fc1w_h = (unsigned short*)ws;  ws += (size_t)3072 * 768 * 2;
  unsigned short* fc1w_l = (unsigned short*)ws;  ws += (size_t)3072 * 768 * 2;
  unsigned short* fc2w_h = (unsigned short*)ws;  ws += (size_t)768 * 3072 * 2;
  unsigned short* fc2w_l = (unsigned short*)ws;  ws += (size_t)768 * 3072 * 2;
  unsigned short* h_h    = (unsigned short*)ws;  ws += (size_t)4096 * 768 * 2;
  unsigned short* h_l    = (unsigned short*)ws;  ws += (size_t)4096 * 768 * 2;
  unsigned short* y_h    = (unsigned short*)ws;  ws += (size_t)4096 * 768 * 2;
  unsigned short* y_l    = (unsigned short*)ws;  ws += (size_t)4096 * 768 * 2;
  float*          x1     = (float*)ws;           ws += (size_t)4096 * 768 * 4;
  unsigned short* big    = (unsigned short*)ws;  // qkv (18.9MB) then fc1-out g (25.2MB)
  unsigned short* qkv_bf = big;
  unsigned short* g_bf   = big;

  // weight transposes (f32 [K][N] -> split bf16 [N][K])
  transpose_cast_split<<<dim3(72, 24), 256, 0, stream>>>(qkvw, qkvw_h, qkvw_l, 768, 2304);
  transpose_cast_split<<<dim3(24, 24), 256, 0, stream>>>(outw, outw_h, outw_l, 768, 768);
  transpose_cast_split<<<dim3(96, 24), 256, 0, stream>>>(fc1w, fc1w_h, fc1w_l, 768, 3072);
  transpose_cast_split<<<dim3(24, 96), 256, 0, stream>>>(fc2w, fc2w_h, fc2w_l, 3072, 768);

  // h = LN(x), split
  ln_split<<<4096, 192, 0, stream>>>(x, ln1w, ln1b, h_h, h_l);
  // qkv = h @ qkv_w + qkv_b  (f32-grade, bf16 out)
  gemm_bt<0, 1><<<dim3(18, 32), 256, 0, stream>>>(h_h, h_l, qkvw_h, qkvw_l, qkvb, nullptr,
                                                  qkv_bf, 4096, 2304, 768);
  // y = attention(qkv), split out
  attn_kernel<<<dim3(32, 24), 256, 0, stream>>>(qkv_bf, y_h, y_l);
  // x1 = x + y @ out_w + out_b
  gemm_bt<2, 1><<<dim3(6, 32), 256, 0, stream>>>(y_h, y_l, outw_h, outw_l, outb, x,
                                                 x1, 4096, 768, 768);
  // h = LN(x1), split
  ln_split<<<4096, 192, 0, stream>>>(x1, ln1w, ln1b, h_h, h_l);
  // g = gelu(h @ fc1_w + fc1_b)  (bf16 out)
  gemm_bt<1, 1><<<dim3(24, 32), 256, 0, stream>>>(h_h, h_l, fc1w_h, fc1w_l, fc1b, nullptr,
                                                  g_bf, 4096, 3072, 768);
  // out = x1 + g @ fc2_w + fc2_b
  gemm_bt<2, 0><<<dim3(6, 32), 256, 0, stream>>>(g_bf, nullptr, fc2w_h, fc2w_l, fc2b, x1,
                                                 outp, 4096, 768, 3072);
}

// Round 3
// 430.049 us; speedup vs baseline: 1.1455x; 1.1455x over previous
//
#include <hip/hip_runtime.h>
#include <hip/hip_bf16.h>

typedef __attribute__((ext_vector_type(8))) short bf16x8;
typedef __attribute__((ext_vector_type(8))) unsigned short u16x8;
typedef __attribute__((ext_vector_type(4))) float f32x4;

__device__ __forceinline__ f32x4 mfma16(bf16x8 a, bf16x8 b, f32x4 c) {
  return __builtin_amdgcn_mfma_f32_16x16x32_bf16(a, b, c, 0, 0, 0);
}

__device__ __forceinline__ void gload_lds16(const void* g, void* l) {
  __builtin_amdgcn_global_load_lds(
      (__attribute__((address_space(1))) void*)(g),
      (__attribute__((address_space(3))) void*)(l), 16, 0, 0);
}

__device__ __forceinline__ unsigned short f2bf(float f) {
  union { __hip_bfloat16 h; unsigned short u; } cv;
  cv.h = __float2bfloat16(f);
  return cv.u;
}

__device__ __forceinline__ void split2(float v, unsigned short& hb, unsigned short& lb) {
  __hip_bfloat16 hh = __float2bfloat16(v);
  union { __hip_bfloat16 h; unsigned short u; } cv;
  cv.h = hh;
  hb = cv.u;
  lb = f2bf(v - __bfloat162float(hh));
}

__device__ __forceinline__ float gelu_f(float v) {
  float u = 0.7978845608028654f * (v + 0.044715f * v * v * v);
  return 0.5f * v * (1.0f + tanhf(u));
}

// ---------------- transpose + cast split: W f32 [K][N] -> hi/lo bf16 [N][K] ----------------
__global__ __launch_bounds__(256) void transpose_cast_split(
    const float* __restrict__ in, unsigned short* __restrict__ outh,
    unsigned short* __restrict__ outl, int K, int N) {
  __shared__ float tile[32][33];
  const int n0 = blockIdx.x * 32, k0 = blockIdx.y * 32;
  const int tx = threadIdx.x & 31, ty = threadIdx.x >> 5;  // ty 0..7
#pragma unroll
  for (int i = 0; i < 32; i += 8)
    tile[ty + i][tx] = in[(size_t)(k0 + ty + i) * N + (n0 + tx)];
  __syncthreads();
#pragma unroll
  for (int i = 0; i < 32; i += 8) {
    unsigned short hb, lb;
    split2(tile[tx][ty + i], hb, lb);
    const size_t idx = (size_t)(n0 + ty + i) * K + (k0 + tx);
    outh[idx] = hb;
    outl[idx] = lb;
  }
}

// ---------------- LayerNorm (C=768) f32 -> split bf16 ----------------
__global__ __launch_bounds__(192) void ln_split(
    const float* __restrict__ x, const float* __restrict__ w,
    const float* __restrict__ bb, unsigned short* __restrict__ outh,
    unsigned short* __restrict__ outl) {
  const int row = blockIdx.x;
  const int t = threadIdx.x;  // 0..191, 4 floats each
  const float4 v = ((const float4*)(x + (size_t)row * 768))[t];
  float s = v.x + v.y + v.z + v.w;
  float q = v.x * v.x + v.y * v.y + v.z * v.z + v.w * v.w;
#pragma unroll
  for (int off = 1; off < 64; off <<= 1) {
    s += __shfl_xor(s, off);
    q += __shfl_xor(q, off);
  }
  __shared__ float ss[3], qq[3];
  const int wid = t >> 6;
  if ((t & 63) == 0) { ss[wid] = s; qq[wid] = q; }
  __syncthreads();
  const float S = ss[0] + ss[1] + ss[2];
  const float Q = qq[0] + qq[1] + qq[2];
  const float mu = S * (1.0f / 768.0f);
  const float var = Q * (1.0f / 768.0f) - mu * mu;
  const float rstd = rsqrtf(var + 1e-5f);
  const float4 wv = ((const float4*)w)[t];
  const float4 bv = ((const float4*)bb)[t];
  float r0 = (v.x - mu) * rstd * wv.x + bv.x;
  float r1 = (v.y - mu) * rstd * wv.y + bv.y;
  float r2 = (v.z - mu) * rstd * wv.z + bv.z;
  float r3 = (v.w - mu) * rstd * wv.w + bv.w;
  ushort4 oh, ol;
  split2(r0, oh.x, ol.x);
  split2(r1, oh.y, ol.y);
  split2(r2, oh.z, ol.z);
  split2(r3, oh.w, ol.w);
  ((ushort4*)(outh + (size_t)row * 768))[t] = oh;
  ((ushort4*)(outl + (size_t)row * 768))[t] = ol;
}

// ---------------- GEMM: C = A * Bt^T + bias (split-bf16 operands, f32-grade) ----------------
// EPI 0: bf16 store; 1: gelu + bf16 store; 2: f32 store with f32 residual add
// ASPLIT 1: A has hi+lo (3 mfma); 0: A hi only (2 mfma).
template <int EPI, int ASPLIT>
__global__ __launch_bounds__(256) void gemm_bt(
    const unsigned short* __restrict__ Ah, const unsigned short* __restrict__ Al,
    const unsigned short* __restrict__ Bh, const unsigned short* __restrict__ Bl,
    const float* __restrict__ bias, const float* __restrict__ resid,
    void* __restrict__ outp, int M, int N, int K) {
  __shared__ __align__(16) unsigned short ldsAh[128 * 32];
  __shared__ __align__(16) unsigned short ldsAl[128 * 32];
  __shared__ __align__(16) unsigned short ldsBh[128 * 32];
  __shared__ __align__(16) unsigned short ldsBl[128 * 32];
  const int tid = threadIdx.x;
  const int lane = tid & 63, wid = tid >> 6;
  const int wr = wid >> 1, wc = wid & 1;  // wave -> 64x64 sub-tile
  const int m0 = blockIdx.y * 128, n0 = blockIdx.x * 128;
  const int srow = lane >> 2, sk = (lane & 3) * 8;  // staging: 16 rows/wave, 16B/lane
  const size_t arow = (size_t)(m0 + wid * 16 + srow) * K + sk;
  const size_t brow = (size_t)(n0 + wid * 16 + srow) * K + sk;
  const unsigned short* Agh = Ah + arow;
  const unsigned short* Agl = Al + arow;  // valid only if ASPLIT
  const unsigned short* Bgh = Bh + brow;
  const unsigned short* Bgl = Bl + brow;
  char* AhW = (char*)ldsAh + wid * 1024;
  char* AlW = (char*)ldsAl + wid * 1024;
  char* BhW = (char*)ldsBh + wid * 1024;
  char* BlW = (char*)ldsBl + wid * 1024;
  const int rl = lane & 15, g = lane >> 4;
  const int koff = g * 16;  // byte offset of k-chunk within 64B row

  f32x4 acc[4][4];
#pragma unroll
  for (int m = 0; m < 4; ++m)
#pragma unroll
    for (int n = 0; n < 4; ++n) acc[m][n] = 0.0f;

  for (int k0 = 0; k0 < K; k0 += 32) {
    gload_lds16(Agh, AhW);
    gload_lds16(Agh + (size_t)64 * K, AhW + 4096);
    if (ASPLIT) {
      gload_lds16(Agl, AlW);
      gload_lds16(Agl + (size_t)64 * K, AlW + 4096);
      Agl += 32;
    }
    gload_lds16(Bgh, BhW);
    gload_lds16(Bgh + (size_t)64 * K, BhW + 4096);
    gload_lds16(Bgl, BlW);
    gload_lds16(Bgl + (size_t)64 * K, BlW + 4096);
    Agh += 32;
    Bgh += 32;
    Bgl += 32;
    __syncthreads();
    bf16x8 fah[4], fal[4], fbh[4], fbl[4];
#pragma unroll
    for (int m = 0; m < 4; ++m) {
      const int off = (wr * 64 + m * 16 + rl) * 64 + koff;
      fah[m] = *(const bf16x8*)((const char*)ldsAh + off);
      if (ASPLIT) fal[m] = *(const bf16x8*)((const char*)ldsAl + off);
    }
#pragma unroll
    for (int n = 0; n < 4; ++n) {
      const int off = (wc * 64 + n * 16 + rl) * 64 + koff;
      fbh[n] = *(const bf16x8*)((const char*)ldsBh + off);
      fbl[n] = *(const bf16x8*)((const char*)ldsBl + off);
    }
#pragma unroll
    for (int m = 0; m < 4; ++m)
#pragma unroll
      for (int n = 0; n < 4; ++n) {
        acc[m][n] = mfma16(fah[m], fbh[n], acc[m][n]);
        acc[m][n] = mfma16(fah[m], fbl[n], acc[m][n]);
        if (ASPLIT) acc[m][n] = mfma16(fal[m], fbh[n], acc[m][n]);
      }
    __syncthreads();
  }

  __hip_bfloat16* outb16 = (__hip_bfloat16*)outp;
  float* outf = (float*)outp;
#pragma unroll
  for (int n = 0; n < 4; ++n) {
    const int col = n0 + wc * 64 + n * 16 + rl;
    const float bia = bias[col];
#pragma unroll
    for (int m = 0; m < 4; ++m) {
      const int row_base = m0 + wr * 64 + m * 16 + g * 4;
#pragma unroll
      for (int r = 0; r < 4; ++r) {
        float val = acc[m][n][r] + bia;
        const size_t idx = (size_t)(row_base + r) * N + col;
        if (EPI == 1) val = gelu_f(val);
        if (EPI == 2)
          outf[idx] = resid[idx] + val;
        else
          outb16[idx] = __float2bfloat16(val);
      }
    }
  }
}

// ---------------- fused causal attention (flash-style, KVBLK=64, prefetched) ----------------
// qkv bf16 [B*T, 2304]; y split bf16 [B*T, 768]. grid (32 qtiles paired, 24 bh), 256 thr.
__global__ __launch_bounds__(256) void attn_kernel(
    const unsigned short* __restrict__ qkv, unsigned short* __restrict__ yh,
    unsigned short* __restrict__ yl) {
  const int T = 2048, C3 = 2304, NH = 12;
  const int bx = blockIdx.x, bh = blockIdx.y;
  const int qt = (bx & 1) ? (31 - (bx >> 1)) : (bx >> 1);  // long/short pairing
  const int b = bh / NH, h = bh % NH;
  const int tid = threadIdx.x, lane = tid & 63, w = tid >> 6;
  const int rl = lane & 15, g = lane >> 4;
  // XOR-swizzled LDS: 16B block index ^= (row&7)
  __shared__ __align__(16) unsigned short Kl[64 * 64];     // [kv][d]
  __shared__ __align__(16) unsigned short Vt[64 * 64];     // [d][kv]
  __shared__ __align__(16) unsigned short Pl[4][16 * 64];  // per-wave [q][kv]
  const size_t base = (size_t)b * T * C3;
  const int hq = h * 64, hk = 768 + h * 64, hv = 1536 + h * 64;
  const int qr0 = qt * 64 + w * 16;

  bf16x8 qf[2];
#pragma unroll
  for (int c = 0; c < 2; ++c)
    qf[c] = *(const bf16x8*)(qkv + base + (size_t)(qr0 + rl) * C3 + hq + 32 * c + 8 * g);

  // staging assignment
  const int krow = tid >> 2, ktb = tid & 3;   // K: 64 rows x 4 thr (32B each)
  const int vr = tid & 31, vdg = tid >> 5;    // V: kv pair {2vr,2vr+1}, d rows vdg*8..+7
  const unsigned short* Kg = qkv + base + (size_t)krow * C3 + hk + ktb * 16;
  const unsigned short* Vg = qkv + base + (size_t)(2 * vr) * C3 + hv + vdg * 8;

  f32x4 o[4];
  float m_r[4], s_r[4];
#pragma unroll
  for (int i = 0; i < 4; ++i) { o[i] = 0.0f; m_r[i] = -1e30f; s_r[i] = 0.0f; }

  const int nt = qt + 1;
  // prologue: prefetch tile 0 into regs
  bf16x8 kp0 = *(const bf16x8*)(Kg);
  bf16x8 kp1 = *(const bf16x8*)(Kg + 8);
  u16x8 vp0 = *(const u16x8*)(Vg);
  u16x8 vp1 = *(const u16x8*)(Vg + C3);

  for (int t = 0; t < nt; ++t) {
    __syncthreads();  // LDS free (prev tile's compute done)
    // write prefetched regs -> swizzled LDS
    *(bf16x8*)((char*)Kl + krow * 128 + (((ktb * 2) ^ (krow & 7)) << 4)) = kp0;
    *(bf16x8*)((char*)Kl + krow * 128 + (((ktb * 2 + 1) ^ (krow & 7)) << 4)) = kp1;
#pragma unroll
    for (int i = 0; i < 8; ++i) {
      const int d = vdg * 8 + i;
      *(unsigned int*)((char*)Vt + d * 128 + ((vr * 4) ^ (i << 4))) =
          (unsigned int)vp0[i] | ((unsigned int)vp1[i] << 16);
    }
    __syncthreads();  // LDS ready
    if (t + 1 < nt) {  // prefetch next tile
      const unsigned short* nk = Kg + (size_t)(t + 1) * 64 * C3;
      const unsigned short* nv = Vg + (size_t)(t + 1) * 64 * C3;
      kp0 = *(const bf16x8*)(nk);
      kp1 = *(const bf16x8*)(nk + 8);
      vp0 = *(const u16x8*)(nv);
      vp1 = *(const u16x8*)(nv + C3);
    }

    // ---- S = Q K^T : 4 kv-chunks of 16, 2 d-chunks of 32 ----
    f32x4 s[4];
#pragma unroll
    for (int ch = 0; ch < 4; ++ch) s[ch] = 0.0f;
#pragma unroll
    for (int c = 0; c < 2; ++c)
#pragma unroll
      for (int ch = 0; ch < 4; ++ch) {
        bf16x8 kb = *(const bf16x8*)((char*)Kl + (ch * 16 + rl) * 128 +
                                     ((((c << 2) | g) ^ (rl & 7)) << 4));
        s[ch] = mfma16(qf[c], kb, s[ch]);
      }

    // ---- online softmax (row q = g*4+r, kv cols = ch*16+rl) ----
    const bool diag = (t == nt - 1);
    const int kv0 = t * 64;
    unsigned short* Pw = Pl[w];
#pragma unroll
    for (int r = 0; r < 4; ++r) {
      const int q = g * 4 + r;
      const int qrow = qr0 + q;
      float v0 = s[0][r] * 0.125f, v1 = s[1][r] * 0.125f;
      float v2 = s[2][r] * 0.125f, v3 = s[3][r] * 0.125f;
      if (diag) {
        v0 = (kv0 + 0 + rl > qrow) ? -1e30f : v0;
        v1 = (kv0 + 16 + rl > qrow) ? -1e30f : v1;
        v2 = (kv0 + 32 + rl > qrow) ? -1e30f : v2;
        v3 = (kv0 + 48 + rl > qrow) ? -1e30f : v3;
      }
      float mx = fmaxf(fmaxf(v0, v1), fmaxf(v2, v3));
#pragma unroll
      for (int off = 1; off < 16; off <<= 1) mx = fmaxf(mx, __shfl_xor(mx, off));
      const float mnew = fmaxf(m_r[r], mx);
      const float fs = __expf(m_r[r] - mnew);
      const float p0 = __expf(v0 - mnew);
      const float p1 = __expf(v1 - mnew);
      const float p2 = __expf(v2 - mnew);
      const float p3 = __expf(v3 - mnew);
      float rs = (p0 + p1) + (p2 + p3);
#pragma unroll
      for (int off = 1; off < 16; off <<= 1) rs += __shfl_xor(rs, off);
      s_r[r] = s_r[r] * fs + rs;
      m_r[r] = mnew;
#pragma unroll
      for (int nf = 0; nf < 4; ++nf) o[nf][r] *= fs;
      const int sw = (q & 7) << 4;
      *(unsigned short*)((char*)Pw + q * 128 + ((0 + rl * 2) ^ sw)) = f2bf(p0);
      *(unsigned short*)((char*)Pw + q * 128 + ((32 + rl * 2) ^ sw)) = f2bf(p1);
      *(unsigned short*)((char*)Pw + q * 128 + ((64 + rl * 2) ^ sw)) = f2bf(p2);
      *(unsigned short*)((char*)Pw + q * 128 + ((96 + rl * 2) ^ sw)) = f2bf(p3);
    }

    // ---- O += P V  (per-wave P buffer: same-wave ds dependency, no barrier) ----
#pragma unroll
    for (int kb = 0; kb < 2; ++kb) {
      bf16x8 pa = *(const bf16x8*)((char*)Pw + rl * 128 +
                                   ((((kb << 2) | g) ^ (rl & 7)) << 4));
#pragma unroll
      for (int nf = 0; nf < 4; ++nf) {
        bf16x8 vb = *(const bf16x8*)((char*)Vt + (nf * 16 + rl) * 128 +
                                     ((((kb << 2) | g) ^ (rl & 7)) << 4));
        o[nf] = mfma16(pa, vb, o[nf]);
      }
    }
  }

#pragma unroll
  for (int r = 0; r < 4; ++r) {
    const float inv = 1.0f / s_r[r];
#pragma unroll
    for (int nf = 0; nf < 4; ++nf) {
      const float val = o[nf][r] * inv;
      const size_t idx = (size_t)(b * T + qr0 + g * 4 + r) * 768 + hq + nf * 16 + rl;
      unsigned short hb, lb;
      split2(val, hb, lb);
      yh[idx] = hb;
      yl[idx] = lb;
    }
  }
}

// ---------------- host launch ----------------
extern "C" void kernel_launch(void* const* d_in, const int* in_sizes, int n_in,
                              void* d_out, int out_size, void* d_ws, size_t ws_size,
                              hipStream_t stream) {
  const float* x    = (const float*)d_in[0];
  const float* ln1w = (const float*)d_in[1];
  const float* ln1b = (const float*)d_in[2];
  const float* qkvw = (const float*)d_in[3];
  const float* qkvb = (const float*)d_in[4];
  const float* outw = (const float*)d_in[5];
  const float* outb = (const float*)d_in[6];
  const float* fc1w = (const float*)d_in[7];
  const float* fc1b = (const float*)d_in[8];
  const float* fc2w = (const float*)d_in[9];
  const float* fc2b = (const float*)d_in[10];
  float* outp = (float*)d_out;

  char* ws = (char*)d_ws;
  unsigned short* qkvw_h = (unsigned short*)ws;  ws += (size_t)2304 * 768 * 2;
  unsigned short* qkvw_l = (unsigned short*)ws;  ws += (size_t)2304 * 768 * 2;
  unsigned short* outw_h = (unsigned short*)ws;  ws += (size_t)768 * 768 * 2;
  unsigned short* outw_l = (unsigned short*)ws;  ws += (size_t)768 * 768 * 2;
  unsigned short* fc1w_h = (unsigned short*)ws;  ws += (size_t)3072 * 768 * 2;
  unsigned short* fc1w_l = (unsigned short*)ws;  ws += (size_t)3072 * 768 * 2;
  unsigned short* fc2w_h = (unsigned short*)ws;  ws += (size_t)768 * 3072 * 2;
  unsigned short* fc2w_l = (unsigned short*)ws;  ws += (size_t)768 * 3072 * 2;
  unsigned short* h_h    = (unsigned short*)ws;  ws += (size_t)4096 * 768 * 2;
  unsigned short* h_l    = (unsigned short*)ws;  ws += (size_t)4096 * 768 * 2;
  unsigned short* y_h    = (unsigned short*)ws;  ws += (size_t)4096 * 768 * 2;
  unsigned short* y_l    = (unsigned short*)ws;  ws += (size_t)4096 * 768 * 2;
  float*          x1     = (float*)ws;           ws += (size_t)4096 * 768 * 4;
  unsigned short* big    = (unsigned short*)ws;  // qkv (18.9MB) then fc1-out g (25.2MB)
  unsigned short* qkv_bf = big;
  unsigned short* g_bf   = big;

  // weight transposes (f32 [K][N] -> split bf16 [N][K])
  transpose_cast_split<<<dim3(72, 24), 256, 0, stream>>>(qkvw, qkvw_h, qkvw_l, 768, 2304);
  transpose_cast_split<<<dim3(24, 24), 256, 0, stream>>>(outw, outw_h, outw_l, 768, 768);
  transpose_cast_split<<<dim3(96, 24), 256, 0, stream>>>(fc1w, fc1w_h, fc1w_l, 768, 3072);
  transpose_cast_split<<<dim3(24, 96), 256, 0, stream>>>(fc2w, fc2w_h, fc2w_l, 3072, 768);

  // h = LN(x), split
  ln_split<<<4096, 192, 0, stream>>>(x, ln1w, ln1b, h_h, h_l);
  // qkv = h @ qkv_w + qkv_b  (f32-grade, bf16 out)
  gemm_bt<0, 1><<<dim3(18, 32), 256, 0, stream>>>(h_h, h_l, qkvw_h, qkvw_l, qkvb, nullptr,
                                                  qkv_bf, 4096, 2304, 768);
  // y = attention(qkv), split out
  attn_kernel<<<dim3(32, 24), 256, 0, stream>>>(qkv_bf, y_h, y_l);
  // x1 = x + y @ out_w + out_b
  gemm_bt<2, 1><<<dim3(6, 32), 256, 0, stream>>>(y_h, y_l, outw_h, outw_l, outb, x,
                                                 x1, 4096, 768, 768);
  // h = LN(x1), split
  ln_split<<<4096, 192, 0, stream>>>(x1, ln1w, ln1b, h_h, h_l);
  // g = gelu(h @ fc1_w + fc1_b)  (bf16 out)
  gemm_bt<1, 1><<<dim3(24, 32), 256, 0, stream>>>(h_h, h_l, fc1w_h, fc1w_l, fc1b, nullptr,
                                                  g_bf, 4096, 3072, 768);
  // out = x1 + g @ fc2_w + fc2_b
  gemm_bt<2, 0><<<dim3(6, 32), 256, 0, stream>>>(g_bf, nullptr, fc2w_h, fc2w_l, fc2b, x1,
                                                 outp, 4096, 768, 3072);
}